// Round 1
// 493.883 us; speedup vs baseline: 1.0776x; 1.0776x over previous
//
#include <hip/hip_runtime.h>
#include <hip/hip_bf16.h>

// MoE layer, routed top-2 implementation.
// N=4096 tokens, D=768, F=3072, E=8. All inputs fp32; compute in f16 MFMA
// (fp32 accumulate), gating in fp64 for exact top-2 selection.

#define N_TOK 4096
#define DIM   768
#define FDIM  3072
#define NEXP  8

typedef __attribute__((ext_vector_type(8))) _Float16 f16x8;
typedef __attribute__((ext_vector_type(4))) _Float16 f16x4;
typedef __attribute__((ext_vector_type(4))) float     f32x4;

__device__ __forceinline__ float gelu_exact(float v) {
    return 0.5f * v * (1.0f + erff(v * 0.7071067811865475f));
}

// async global->LDS, 16B per lane. Dest must be wave-uniform base + lane*16
// (our staging layout As[t>>2][(t&3)*8] is exactly linear in lane order).
__device__ __forceinline__ void gload_lds16(const _Float16* g, _Float16* l) {
    __builtin_amdgcn_global_load_lds(
        (const __attribute__((address_space(1))) void*)g,
        (__attribute__((address_space(3))) void*)l,
        16, 0, 0);
}

// ---------------- cast x (fp32 -> f16), vectorized ----------------
__global__ __launch_bounds__(256) void cast_x_kernel(const float* __restrict__ x,
                                                     _Float16* __restrict__ xh) {
    int i = blockIdx.x * 256 + threadIdx.x;   // one float4 per thread, grid sized exactly
    float4 v = ((const float4*)x)[i];
    f16x4 o;
    o[0] = (_Float16)v.x; o[1] = (_Float16)v.y;
    o[2] = (_Float16)v.z; o[3] = (_Float16)v.w;
    ((f16x4*)xh)[i] = o;
}

// ---------------- transpose + cast: fp32 [E][R][C] -> f16 [E][C][R] ----------------
__global__ __launch_bounds__(256) void transpose_cast_kernel(const float* __restrict__ in,
                                                             _Float16* __restrict__ out,
                                                             int R, int C) {
    const int e  = blockIdx.z;
    const size_t eoff = (size_t)e * R * C;
    const int c0 = blockIdx.x * 64;
    const int r0 = blockIdx.y * 64;
    __shared__ _Float16 tile[64][66];   // pitch 66 to soften bank conflicts
    const int t = threadIdx.x;
    #pragma unroll
    for (int it = 0; it < 4; it++) {
        int lin = it * 256 + t;
        int r  = lin >> 4;       // 0..63
        int c4 = lin & 15;       // float4 column group
        float4 v = *(const float4*)&in[eoff + (size_t)(r0 + r) * C + c0 + c4 * 4];
        tile[r][c4 * 4 + 0] = (_Float16)v.x;
        tile[r][c4 * 4 + 1] = (_Float16)v.y;
        tile[r][c4 * 4 + 2] = (_Float16)v.z;
        tile[r][c4 * 4 + 3] = (_Float16)v.w;
    }
    __syncthreads();
    #pragma unroll
    for (int it = 0; it < 4; it++) {
        int lin = it * 256 + t;
        int c  = lin >> 4;       // out row (= original column)
        int r4 = lin & 15;       // group of 4 original rows
        f16x4 o;
        #pragma unroll
        for (int j = 0; j < 4; j++) o[j] = tile[r4 * 4 + j][c];
        *(f16x4*)&out[eoff + (size_t)(c0 + c) * R + r0 + r4 * 4] = o;
    }
}

// ---------------- gating: fp64 logits, softmax, top-2, per-expert lists ----------------
__global__ __launch_bounds__(256) void gate_kernel(const float* __restrict__ x,
                                                   const float* __restrict__ gw,
                                                   const float* __restrict__ gb,
                                                   int* __restrict__ tok_list,
                                                   float* __restrict__ wt_list,
                                                   int* __restrict__ count) {
    const int gtid = blockIdx.x * 256 + threadIdx.x;
    const int n    = gtid >> 6;        // one wave per token
    const int lane = threadIdx.x & 63;
    if (n >= N_TOK) return;
    double part[NEXP];
    #pragma unroll
    for (int e = 0; e < NEXP; e++) part[e] = 0.0;
    for (int d = lane; d < DIM; d += 64) {
        float xv = x[n * DIM + d];
        const float* g = &gw[d * NEXP];
        #pragma unroll
        for (int e = 0; e < NEXP; e++) part[e] += (double)xv * (double)g[e];
    }
    #pragma unroll
    for (int e = 0; e < NEXP; e++) {
        double v = part[e];
        #pragma unroll
        for (int off = 32; off > 0; off >>= 1) v += __shfl_xor(v, off);
        part[e] = v + (double)gb[e];
    }
    if (lane == 0) {
        double mx = part[0];
        #pragma unroll
        for (int e = 1; e < NEXP; e++) mx = fmax(mx, part[e]);
        double ex[NEXP]; double s = 0.0;
        #pragma unroll
        for (int e = 0; e < NEXP; e++) { ex[e] = exp(part[e] - mx); s += ex[e]; }
        int i0 = 0;
        #pragma unroll
        for (int e = 1; e < NEXP; e++) if (ex[e] > ex[i0]) i0 = e;   // first-max tie-break, matches top_k
        int i1 = (i0 == 0) ? 1 : 0;
        #pragma unroll
        for (int e = 0; e < NEXP; e++) if (e != i0 && ex[e] > ex[i1]) i1 = e;
        float g0 = (float)(ex[i0] / s), g1 = (float)(ex[i1] / s);
        float dn = g0 + g1 + 1e-9f;
        float w0 = g0 / dn, w1 = g1 / dn;
        int s0 = atomicAdd(&count[i0], 1);
        tok_list[i0 * N_TOK + s0] = n;  wt_list[i0 * N_TOK + s0] = w0;
        int s1 = atomicAdd(&count[i1], 1);
        tok_list[i1 * N_TOK + s1] = n;  wt_list[i1 * N_TOK + s1] = w1;
    }
}

// ---------------- tiny prefix scan over 8 expert counts ----------------
__global__ void scan_kernel(const int* __restrict__ count, int* __restrict__ basep) {
    if (threadIdx.x == 0) {
        int s = 0;
        for (int e = 0; e < NEXP; e++) { basep[e] = s; s += count[e]; }
    }
}

// ---------------- GEMM1: h = gelu(x_gathered @ w1[e] + b1[e]) ----------------
// 128x128 tile, BK=32, 4 waves (2x2), 4x4 mfma_f32_16x16x32_f16 per wave.
// A: gathered token rows from xh [N][768]; B: w1t [E][F][D] rows (k-contiguous).
// Staging via global_load_lds (m97 2-barrier structure); grid is
// (cols, experts, rowblocks) so live blocks form a dense prefix spread
// across all CUs (old (cols, rows, experts) order piled live blocks on
// the same 192 CUs since 24*32 = 768 = 3*256).
__global__ __launch_bounds__(256) void mm1_kernel(const _Float16* __restrict__ xh,
                                                  const _Float16* __restrict__ w1t,
                                                  const float* __restrict__ bias1,
                                                  const int* __restrict__ tok_list,
                                                  const int* __restrict__ count,
                                                  const int* __restrict__ basep,
                                                  _Float16* __restrict__ h) {
    const int e    = blockIdx.y;
    const int cnt  = count[e];
    const int row0 = blockIdx.z * 128;
    if (row0 >= cnt) return;
    const int col0 = blockIdx.x * 128;
    const int t    = threadIdx.x;
    const int lane = t & 63;
    const int wv   = t >> 6;
    const int wy   = wv >> 1, wx = wv & 1;
    const int m_lane = lane & 15, quad = lane >> 4;

    __shared__ __align__(16) _Float16 As[128][32];
    __shared__ __align__(16) _Float16 Bs[128][32];

    const int srow = t >> 2;            // 0..63 staging row
    const int kin  = (t & 3) * 8;       // 8-elem k chunk

    int i0 = row0 + srow;      if (i0 > cnt - 1) i0 = cnt - 1;
    int i1 = row0 + 64 + srow; if (i1 > cnt - 1) i1 = cnt - 1;
    const int tokA0 = tok_list[e * N_TOK + i0];
    const int tokA1 = tok_list[e * N_TOK + i1];
    const _Float16* pa0 = xh + (size_t)tokA0 * DIM + kin;
    const _Float16* pa1 = xh + (size_t)tokA1 * DIM + kin;
    const _Float16* pb0 = w1t + (size_t)e * FDIM * DIM + (size_t)(col0 + srow) * DIM + kin;
    const _Float16* pb1 = pb0 + (size_t)64 * DIM;

    f32x4 acc[4][4];
    #pragma unroll
    for (int i = 0; i < 4; i++)
        #pragma unroll
        for (int j = 0; j < 4; j++)
            acc[i][j] = (f32x4){0.f, 0.f, 0.f, 0.f};

    for (int kk = 0; kk < DIM; kk += 32) {
        __syncthreads();                    // previous tile's reads done
        gload_lds16(pa0 + kk, &As[srow][kin]);
        gload_lds16(pa1 + kk, &As[64 + srow][kin]);
        gload_lds16(pb0 + kk, &Bs[srow][kin]);
        gload_lds16(pb1 + kk, &Bs[64 + srow][kin]);
        __syncthreads();                    // vmcnt(0) drain before barrier
        f16x8 af[4], bf[4];
        #pragma unroll
        for (int i = 0; i < 4; i++)
            af[i] = *(const f16x8*)&As[wy * 64 + i * 16 + m_lane][quad * 8];
        #pragma unroll
        for (int j = 0; j < 4; j++)
            bf[j] = *(const f16x8*)&Bs[wx * 64 + j * 16 + m_lane][quad * 8];
        #pragma unroll
        for (int i = 0; i < 4; i++)
            #pragma unroll
            for (int j = 0; j < 4; j++)
                acc[i][j] = __builtin_amdgcn_mfma_f32_16x16x32_f16(af[i], bf[j], acc[i][j], 0, 0, 0);
    }

    const int hbase = basep[e];
    #pragma unroll
    for (int i = 0; i < 4; i++) {
        #pragma unroll
        for (int r = 0; r < 4; r++) {
            int rl = wy * 64 + i * 16 + quad * 4 + r;   // C/D: row=(lane>>4)*4+reg
            int gr = row0 + rl;
            if (gr < cnt) {
                _Float16* hrow = h + (size_t)(hbase + gr) * FDIM;
                #pragma unroll
                for (int j = 0; j < 4; j++) {
                    int c = col0 + wx * 64 + j * 16 + m_lane;   // C/D: col=lane&15
                    float v = acc[i][j][r] + bias1[e * FDIM + c];
                    hrow[c] = (_Float16)gelu_exact(v);
                }
            }
        }
    }
}

// ---------------- GEMM2: out += gate_w * (h @ w2[e] + b2[e]) ----------------
__global__ __launch_bounds__(256) void mm2_kernel(const _Float16* __restrict__ h,
                                                  const _Float16* __restrict__ w2t,
                                                  const float* __restrict__ bias2,
                                                  const int* __restrict__ tok_list,
                                                  const float* __restrict__ wt_list,
                                                  const int* __restrict__ count,
                                                  const int* __restrict__ basep,
                                                  float* __restrict__ out) {
    const int e    = blockIdx.y;
    const int cnt  = count[e];
    const int row0 = blockIdx.z * 128;
    if (row0 >= cnt) return;
    const int col0 = blockIdx.x * 128;
    const int t    = threadIdx.x;
    const int lane = t & 63;
    const int wv   = t >> 6;
    const int wy   = wv >> 1, wx = wv & 1;
    const int m_lane = lane & 15, quad = lane >> 4;

    __shared__ __align__(16) _Float16 As[128][32];
    __shared__ __align__(16) _Float16 Bs[128][32];

    const int srow = t >> 2;
    const int kin  = (t & 3) * 8;

    const int hbase = basep[e];
    int i0 = row0 + srow;      if (i0 > cnt - 1) i0 = cnt - 1;
    int i1 = row0 + 64 + srow; if (i1 > cnt - 1) i1 = cnt - 1;
    const _Float16* pa0 = h + (size_t)(hbase + i0) * FDIM + kin;
    const _Float16* pa1 = h + (size_t)(hbase + i1) * FDIM + kin;
    const _Float16* pb0 = w2t + (size_t)e * DIM * FDIM + (size_t)(col0 + srow) * FDIM + kin;
    const _Float16* pb1 = pb0 + (size_t)64 * FDIM;

    f32x4 acc[4][4];
    #pragma unroll
    for (int i = 0; i < 4; i++)
        #pragma unroll
        for (int j = 0; j < 4; j++)
            acc[i][j] = (f32x4){0.f, 0.f, 0.f, 0.f};

    for (int kk = 0; kk < FDIM; kk += 32) {
        __syncthreads();
        gload_lds16(pa0 + kk, &As[srow][kin]);
        gload_lds16(pa1 + kk, &As[64 + srow][kin]);
        gload_lds16(pb0 + kk, &Bs[srow][kin]);
        gload_lds16(pb1 + kk, &Bs[64 + srow][kin]);
        __syncthreads();
        f16x8 af[4], bf[4];
        #pragma unroll
        for (int i = 0; i < 4; i++)
            af[i] = *(const f16x8*)&As[wy * 64 + i * 16 + m_lane][quad * 8];
        #pragma unroll
        for (int j = 0; j < 4; j++)
            bf[j] = *(const f16x8*)&Bs[wx * 64 + j * 16 + m_lane][quad * 8];
        #pragma unroll
        for (int i = 0; i < 4; i++)
            #pragma unroll
            for (int j = 0; j < 4; j++)
                acc[i][j] = __builtin_amdgcn_mfma_f32_16x16x32_f16(af[i], bf[j], acc[i][j], 0, 0, 0);
    }

    #pragma unroll
    for (int i = 0; i < 4; i++) {
        #pragma unroll
        for (int r = 0; r < 4; r++) {
            int rl = wy * 64 + i * 16 + quad * 4 + r;
            int gr = row0 + rl;
            if (gr < cnt) {
                int tok   = tok_list[e * N_TOK + gr];
                float wgt = wt_list[e * N_TOK + gr];
                float* orow = out + (size_t)tok * DIM;
                #pragma unroll
                for (int j = 0; j < 4; j++) {
                    int c = col0 + wx * 64 + j * 16 + m_lane;
                    float v = acc[i][j][r] + bias2[e * DIM + c];
                    atomicAdd(&orow[c], wgt * v);
                }
            }
        }
    }
}

extern "C" void kernel_launch(void* const* d_in, const int* in_sizes, int n_in,
                              void* d_out, int out_size, void* d_ws, size_t ws_size,
                              hipStream_t stream) {
    const float* x  = (const float*)d_in[0];
    const float* gw = (const float*)d_in[1];
    const float* gb = (const float*)d_in[2];
    const float* w1 = (const float*)d_in[3];
    const float* b1 = (const float*)d_in[4];
    const float* w2 = (const float*)d_in[5];
    const float* b2 = (const float*)d_in[6];
    float* out = (float*)d_out;

    // workspace layout (all 16B-aligned); total ~132.4 MB
    char* ws = (char*)d_ws;
    _Float16* xh   = (_Float16*)ws;                                    // 4096*768
    _Float16* w1t  = xh  + (size_t)N_TOK * DIM;                        // [E][F][D]
    _Float16* w2t  = w1t + (size_t)NEXP * FDIM * DIM;                  // [E][D][F]
    _Float16* hbuf = w2t + (size_t)NEXP * DIM * FDIM;                  // [2N][F] compact slots
    int*   tok_list = (int*)(hbuf + (size_t)2 * N_TOK * FDIM);         // [E][N]
    float* wt_list  = (float*)(tok_list + NEXP * N_TOK);               // [E][N]
    int*   count    = (int*)(wt_list + NEXP * N_TOK);                  // [E]
    int*   basep    = count + 8;                                       // [E]

    hipMemsetAsync(count, 0, 64, stream);                 // count + base
    hipMemsetAsync(out, 0, (size_t)out_size * sizeof(float), stream);

    cast_x_kernel<<<dim3(N_TOK * DIM / 4 / 256), 256, 0, stream>>>(x, xh);
    // w1: [E][768][3072] -> w1t [E][3072][768]
    transpose_cast_kernel<<<dim3(FDIM / 64, DIM / 64, NEXP), 256, 0, stream>>>(w1, w1t, DIM, FDIM);
    // w2: [E][3072][768] -> w2t [E][768][3072]
    transpose_cast_kernel<<<dim3(DIM / 64, FDIM / 64, NEXP), 256, 0, stream>>>(w2, w2t, FDIM, DIM);
    gate_kernel<<<dim3(N_TOK / 4), 256, 0, stream>>>(x, gw, gb, tok_list, wt_list, count);
    scan_kernel<<<1, 64, 0, stream>>>(count, basep);
    // grid: (cols, experts, rowblocks) -> live blocks are a dense prefix
    mm1_kernel<<<dim3(FDIM / 128, NEXP, N_TOK / 128), 256, 0, stream>>>(
        xh, w1t, b1, tok_list, count, basep, hbuf);
    mm2_kernel<<<dim3(DIM / 128, NEXP, N_TOK / 128), 256, 0, stream>>>(
        hbuf, w2t, b2, tok_list, wt_list, count, basep, out);
}